// Round 4
// baseline (290.703 us; speedup 1.0000x reference)
//
#include <hip/hip_runtime.h>
#include <hip/hip_bf16.h>

// QuantizedLinear: out[64,11008] = x[64,4096] @ (Wq*scale)^T + bias
// R4: barrier-free K-loop, waves-split-K inside a block (no global partials,
// no reduce kernel). Each block streams a 256 KB contiguous weight region;
// each wave: 16 row-streams x 4 KB sequential. x read as bf16 from L2.

#define M_DIM 64
#define N_DIM 11008
#define K_DIM 4096
#define KC (K_DIM / 4)               // 1024 per wave

typedef __attribute__((ext_vector_type(8))) short bf16x8;
typedef __attribute__((ext_vector_type(4))) float f32x4;
typedef __attribute__((ext_vector_type(4))) int i32x4;
typedef __attribute__((ext_vector_type(8))) short s16x8;

// RNE float -> bf16
__device__ __forceinline__ short f2bf(float f) {
    unsigned int u = __builtin_bit_cast(unsigned int, f);
    u = u + 0x7FFFu + ((u >> 16) & 1u);
    return (short)(u >> 16);
}
// int in [-128,127] -> bf16 EXACT
__device__ __forceinline__ short i2bf(int q) {
    float f = (float)q;
    return (short)(__builtin_bit_cast(unsigned int, f) >> 16);
}

// ---- x [64][4096] f32 -> bf16 into ws ----
__global__ __launch_bounds__(256) void convert_x_kernel(const float* __restrict__ x,
                                                        short* __restrict__ xs) {
    int idx = blockIdx.x * 256 + threadIdx.x;   // 32768 threads x 8 elems
    const f32x4* p = (const f32x4*)x + (size_t)idx * 2;
    f32x4 a = p[0], b = p[1];
    s16x8 h;
    h[0] = f2bf(a.x); h[1] = f2bf(a.y); h[2] = f2bf(a.z); h[3] = f2bf(a.w);
    h[4] = f2bf(b.x); h[5] = f2bf(b.y); h[6] = f2bf(b.z); h[7] = f2bf(b.w);
    *((s16x8*)xs + idx) = h;
}

// ---- fused GEMM: 688 blocks x 256 thr; tile M64 x N16; waves split K ----
__global__ __launch_bounds__(256) void qgemm_kernel(const short* __restrict__ xs,
                                                    const int* __restrict__ wq,
                                                    const float* __restrict__ scale_p,
                                                    const float* __restrict__ bias,
                                                    float* __restrict__ out) {
    __shared__ float red[4][16][64];   // [wave][n][m], 16 KB

    const int t    = threadIdx.x;
    const int wv   = t >> 6;
    const int lane = t & 63;
    const int quad = lane >> 4;
    const int l16  = lane & 15;
    const int n0   = blockIdx.x * 16;

    // this wave's K-quarter
    const int kbase = wv * KC;
    // weight stream: row n0+l16, 32 B per lane per k-step (quad-interleaved ->
    // the wave covers 128 B contiguous per row per step, 4 KB sequential total)
    const int* wp = wq + (size_t)(n0 + l16) * K_DIM + kbase + quad * 8;
    // x fragments from L2-resident bf16 copy: A[m = mi*16+l16][k]
    const short* xp = xs + (size_t)l16 * K_DIM + kbase + quad * 8;

    f32x4 acc[4] = {f32x4{0,0,0,0}, f32x4{0,0,0,0}, f32x4{0,0,0,0}, f32x4{0,0,0,0}};

    // prime the pipeline
    i32x4 w0 = __builtin_nontemporal_load((const i32x4*)(wp));
    i32x4 w1 = __builtin_nontemporal_load((const i32x4*)(wp + 4));
    bf16x8 af[4];
    #pragma unroll
    for (int mi = 0; mi < 4; ++mi)
        af[mi] = *(const bf16x8*)(xp + (size_t)mi * 16 * K_DIM);

    for (int kk = 0; kk < KC; kk += 32) {
        // prefetch next iteration (clamped on last iter; values discarded)
        const int nk = (kk + 32 < KC) ? (kk + 32) : kk;
        i32x4 nw0 = __builtin_nontemporal_load((const i32x4*)(wp + nk));
        i32x4 nw1 = __builtin_nontemporal_load((const i32x4*)(wp + nk + 4));
        bf16x8 naf[4];
        #pragma unroll
        for (int mi = 0; mi < 4; ++mi)
            naf[mi] = *(const bf16x8*)(xp + (size_t)mi * 16 * K_DIM + nk);

        // convert current weights -> B fragment (exact)
        bf16x8 bfrag;
        bfrag[0] = i2bf(w0.x); bfrag[1] = i2bf(w0.y);
        bfrag[2] = i2bf(w0.z); bfrag[3] = i2bf(w0.w);
        bfrag[4] = i2bf(w1.x); bfrag[5] = i2bf(w1.y);
        bfrag[6] = i2bf(w1.z); bfrag[7] = i2bf(w1.w);

        #pragma unroll
        for (int mi = 0; mi < 4; ++mi)
            acc[mi] = __builtin_amdgcn_mfma_f32_16x16x32_bf16(af[mi], bfrag, acc[mi], 0, 0, 0);

        w0 = nw0; w1 = nw1;
        #pragma unroll
        for (int mi = 0; mi < 4; ++mi) af[mi] = naf[mi];
    }

    // ---- epilogue: cross-wave K reduction in LDS, fused scale+bias ----
    // C/D layout: D[m = quad*4 + r + 16*mi][n = l16] = acc[mi][r]
    // store transposed red[wv][n][m] so each frag is one b128 write
    #pragma unroll
    for (int mi = 0; mi < 4; ++mi)
        *(f32x4*)&red[wv][l16][mi * 16 + quad * 4] = acc[mi];
    __syncthreads();

    {
        const int n  = t & 15;          // 0..15
        const int mg = t >> 4;          // 0..15 -> m = mg*4 .. +3
        f32x4 s0 = *(const f32x4*)&red[0][n][mg * 4];
        f32x4 s1 = *(const f32x4*)&red[1][n][mg * 4];
        f32x4 s2 = *(const f32x4*)&red[2][n][mg * 4];
        f32x4 s3 = *(const f32x4*)&red[3][n][mg * 4];
        const float sc = *scale_p;
        const float b  = bias[n0 + n];
        #pragma unroll
        for (int j = 0; j < 4; ++j) {
            float v = (s0[j] + s1[j] + s2[j] + s3[j]) * sc + b;
            out[(size_t)(mg * 4 + j) * N_DIM + n0 + n] = v;
        }
    }
}

extern "C" void kernel_launch(void* const* d_in, const int* in_sizes, int n_in,
                              void* d_out, int out_size, void* d_ws, size_t ws_size,
                              hipStream_t stream) {
    const float* x     = (const float*)d_in[0];
    const int*   wq    = (const int*)d_in[1];
    const float* scale = (const float*)d_in[2];
    const float* bias  = (const float*)d_in[3];
    float* out = (float*)d_out;

    short* xs = (short*)d_ws;   // 512 KB bf16 copy of x

    convert_x_kernel<<<128, 256, 0, stream>>>(x, xs);
    qgemm_kernel<<<N_DIM / 16, 256, 0, stream>>>(xs, wq, scale, bias, out);
}